// Round 4
// baseline (321.223 us; speedup 1.0000x reference)
//
#include <hip/hip_runtime.h>
#include <math.h>

#define N_BATCH 8
#define IN_CH   256
#define OUT_CH  256
#define T_LEN   2048
#define DKS     33
#define PAD     16
#define KC      16

#define TT 128        // t per block
#define XS_ROWS 160   // TT + 2*PAD
#define XS_STRIDE 40  // ushort elems per row (80 B, 16B-aligned, banks balanced)

typedef __attribute__((ext_vector_type(8))) short bf16x8;
typedef __attribute__((ext_vector_type(4))) float f32x4;

__device__ __forceinline__ unsigned short f2bf(float f) {
    unsigned u = __builtin_bit_cast(unsigned, f);
    unsigned r = (u + 0x7FFFu + ((u >> 16) & 1u)) >> 16;   // RNE
    return (unsigned short)r;
}

// ---------------------------------------------------------------------------
// Kernel 1: dense conv kernel in bf16, fragment-ready global layout
//   elem(o,i,d) at ((g*8+c)*33+d)*2048 + ai*512 + (q*16+m)*8 + j
// LDS transpose -> all global stores are full-line dwordx4.
// Reference semantics: frac from out-channel 0; second tap dropped when
// p1+1 == 33.
// ---------------------------------------------------------------------------
__global__ __launch_bounds__(64) void build_kern(
    const float* __restrict__ weight,
    const float* __restrict__ P,
    unsigned short* __restrict__ kern_f)
{
    __shared__ unsigned short Ls[DKS * 512];   // 33.8 KB

    const int bid = blockIdx.x;        // 128 blocks
    const int ai = bid & 3;
    const int c  = (bid >> 2) & 7;
    const int g  = bid >> 5;
    const int l  = threadIdx.x;
    const int q  = l >> 4, m = l & 15;
    const int o  = g * 64 + ai * 16 + m;

    for (int j = 0; j < 8; ++j) {
        int i = c * 32 + q * 8 + j;
        float a[DKS];
#pragma unroll
        for (int d = 0; d < DKS; ++d) a[d] = 0.0f;

        const float* Po = P      + (size_t)(o * IN_CH + i) * KC;
        const float* P0 = P      + (size_t)i * KC;          // out-channel 0
        const float* Wo = weight + (size_t)(o * IN_CH + i) * KC;
#pragma unroll
        for (int k = 0; k < KC; ++k) {
            float pp   = Po[k] + (float)(DKS / 2);
            float p0   = P0[k] + (float)(DKS / 2);
            float frac = p0 - floorf(p0);
            int   p1   = (int)floorf(pp);
            float w    = Wo[k];
            a[p1] += w * (1.0f - frac);
            if (p1 + 1 < DKS) a[p1 + 1] += w * frac;
        }
#pragma unroll
        for (int d = 0; d < DKS; ++d)
            Ls[d * 512 + l * 8 + j] = f2bf(a[d]);
    }
    __syncthreads();

    const size_t base = ((size_t)(g * 8 + c) * DKS) * 2048 + (size_t)ai * 512;
#pragma unroll
    for (int d = 0; d < DKS; ++d)
        *(bf16x8*)(kern_f + base + (size_t)d * 2048 + l * 8) =
            *(const bf16x8*)(Ls + d * 512 + l * 8);
}

// ---------------------------------------------------------------------------
// Kernel 2: implicit-GEMM conv, MFMA 16x16x32 bf16.
// 512 blocks, 128 thr = 2 waves. Block tile 64o x 128t; wave tile 64o x 64t
// (acc = 16 frags = 64 VGPRs -- round-3's spill eliminated).
// Per wave per d-step: 4 A-frags (global/L1) feed 16 MFMAs (2x round 2).
// Double-buffered chunk staging: c+1's global loads issue before c's
// 33-step MFMA burst -> fully hidden; one barrier per chunk.
// ---------------------------------------------------------------------------
__global__ __launch_bounds__(128, 1) void dcls_conv(
    const float* __restrict__ x,
    const unsigned short* __restrict__ kern_f,
    const float* __restrict__ bias,
    float* __restrict__ out)
{
    __shared__ unsigned short Xs[2][XS_ROWS * XS_STRIDE];   // 2 x 12.8 KB

    const int id    = blockIdx.x;              // 0..511
    const int og    = (id & 7) >> 1;           // XCD-pinned o-group
    const int rest  = id >> 3;                 // 0..63
    const int batch = rest & 7;
    const int ttile = ((rest >> 3) << 1) | (id & 1);   // 0..15
    const int t0    = ttile * TT;
    const int o0    = og * 64;

    const int tid  = threadIdx.x;
    const int w    = tid >> 6;
    const int l    = tid & 63;
    const int quad = l >> 4;
    const int lm   = l & 15;
    const int wt   = w * 64;

    f32x4 acc[4][4];
#pragma unroll
    for (int a = 0; a < 4; ++a)
#pragma unroll
        for (int b = 0; b < 4; ++b) acc[a][b] = (f32x4){0.f, 0.f, 0.f, 0.f};

    const unsigned short* kf0 = kern_f + ((size_t)og * 8 * DKS) * 2048 + (size_t)l * 8;

    // ---- stage chunk 0 into buf 0 ----
#pragma unroll
    for (int it = 0; it < 20; ++it) {
        int idx = tid + it * 128;          // 0..2559
        int ip  = idx / XS_ROWS;           // i-pair 0..15
        int t   = idx - ip * XS_ROWS;      // 0..159
        int gg  = t0 - PAD + t;
        float v0 = 0.f, v1 = 0.f;
        if ((unsigned)gg < (unsigned)T_LEN) {
            const float* xb = x + ((size_t)(batch * IN_CH + ip * 2)) * T_LEN + gg;
            v0 = xb[0];
            v1 = xb[T_LEN];
        }
        *(unsigned*)(&Xs[0][t * XS_STRIDE + ip * 2]) =
            (unsigned)f2bf(v0) | ((unsigned)f2bf(v1) << 16);
    }
    __syncthreads();

    for (int c = 0; c < 8; ++c) {
        const unsigned short* kfc = kf0 + (size_t)c * DKS * 2048;
        const unsigned short* xsb = &Xs[c & 1][quad * 8];

        // early prefetch for d=0 (issues before the staging block)
        bf16x8 af_c[4], bf_c[4];
#pragma unroll
        for (int a = 0; a < 4; ++a)
            af_c[a] = *(const bf16x8*)(kfc + a * 512);
#pragma unroll
        for (int b = 0; b < 4; ++b)
            bf_c[b] = *(const bf16x8*)(xsb + (wt + b * 16 + lm) * XS_STRIDE);

        // ---- stage chunk c+1 into the other buffer ----
        if (c < 7) {
            const int i0 = (c + 1) * 32;
#pragma unroll
            for (int it = 0; it < 20; ++it) {
                int idx = tid + it * 128;
                int ip  = idx / XS_ROWS;
                int t   = idx - ip * XS_ROWS;
                int gg  = t0 - PAD + t;
                float v0 = 0.f, v1 = 0.f;
                if ((unsigned)gg < (unsigned)T_LEN) {
                    const float* xb = x + ((size_t)(batch * IN_CH + i0 + ip * 2)) * T_LEN + gg;
                    v0 = xb[0];
                    v1 = xb[T_LEN];
                }
                *(unsigned*)(&Xs[(c + 1) & 1][t * XS_STRIDE + ip * 2]) =
                    (unsigned)f2bf(v0) | ((unsigned)f2bf(v1) << 16);
            }
        }

        // ---- 33 d-steps, software-pipelined A (L1) and B (LDS) ----
#pragma unroll
        for (int d = 0; d < DKS; ++d) {
            bf16x8 af_n[4], bf_n[4];
            if (d + 1 < DKS) {
#pragma unroll
                for (int a = 0; a < 4; ++a)
                    af_n[a] = *(const bf16x8*)(kfc + (size_t)(d + 1) * 2048 + a * 512);
#pragma unroll
                for (int b = 0; b < 4; ++b)
                    bf_n[b] = *(const bf16x8*)(xsb + (wt + b * 16 + lm + d + 1) * XS_STRIDE);
            }
#pragma unroll
            for (int a = 0; a < 4; ++a)
#pragma unroll
                for (int b = 0; b < 4; ++b)
                    acc[a][b] = __builtin_amdgcn_mfma_f32_16x16x32_bf16(
                        af_c[a], bf_c[b], acc[a][b], 0, 0, 0);
            if (d + 1 < DKS) {
#pragma unroll
                for (int a = 0; a < 4; ++a) af_c[a] = af_n[a];
#pragma unroll
                for (int b = 0; b < 4; ++b) bf_c[b] = bf_n[b];
            }
        }
        __syncthreads();
    }

    // ---- epilogue ----
#pragma unroll
    for (int a = 0; a < 4; ++a) {
#pragma unroll
        for (int r = 0; r < 4; ++r) {
            int o = o0 + a * 16 + quad * 4 + r;
            float bv = bias[o];
            float* orow = out + ((size_t)(batch * OUT_CH + o)) * T_LEN + t0 + wt + lm;
#pragma unroll
            for (int b = 0; b < 4; ++b)
                orow[b * 16] = acc[a][b][r] + bv;
        }
    }
}

extern "C" void kernel_launch(void* const* d_in, const int* in_sizes, int n_in,
                              void* d_out, int out_size, void* d_ws, size_t ws_size,
                              hipStream_t stream) {
    const float* x      = (const float*)d_in[0];
    const float* weight = (const float*)d_in[1];
    const float* P      = (const float*)d_in[2];
    const float* bias   = (const float*)d_in[3];
    float*       out    = (float*)d_out;
    unsigned short* kern_f = (unsigned short*)d_ws;   // 4.33 MB

    hipLaunchKernelGGL(build_kern, dim3(128), dim3(64), 0, stream,
                       weight, P, kern_f);

    hipLaunchKernelGGL(dcls_conv, dim3(512), dim3(128), 0, stream,
                       x, kern_f, bias, out);
}

// Round 5
// 260.380 us; speedup vs baseline: 1.2337x; 1.2337x over previous
//
#include <hip/hip_runtime.h>
#include <math.h>

#define N_BATCH 8
#define IN_CH   256
#define OUT_CH  256
#define T_LEN   2048
#define DKS     33
#define PAD     16
#define KC      16

#define TT 128        // t per block
#define XS_ROWS 160   // TT + 2*PAD
#define XS_STRIDE 40  // ushort elems per row (80 B, 16B-aligned)

typedef __attribute__((ext_vector_type(8))) short bf16x8;
typedef __attribute__((ext_vector_type(4))) float f32x4;

__device__ __forceinline__ unsigned short f2bf(float f) {
    unsigned u = __builtin_bit_cast(unsigned, f);
    unsigned r = (u + 0x7FFFu + ((u >> 16) & 1u)) >> 16;   // RNE
    return (unsigned short)r;
}

// ---------------------------------------------------------------------------
// Kernel 1 (v4): dense conv kernel in bf16, fragment-ready global layout
//   elem(o,i,d) at ((g*8+c)*33+d)*2048 + ai*512 + (q*16+m)*8 + j
//   g=o>>6, ai=(o>>4)&3, m=o&15, c=i>>5, q=(i&31)>>3, j=i&7.
// 128 blocks x 512 thr: one thread per (l=q*16+m, j) -> 65536 threads
// (v3 had 8192 -> latency-bound ~100us; this is the 8x parallel fix).
// float4 input loads, LDS transpose, coalesced uint stores.
// Reference semantics: frac from out-channel 0; second tap dropped when
// p1+1 == 33.
// ---------------------------------------------------------------------------
__global__ __launch_bounds__(512) void build_kern(
    const float* __restrict__ weight,
    const float* __restrict__ P,
    unsigned short* __restrict__ kern_f)
{
    __shared__ unsigned short Ls[DKS * 512];   // 33.8 KB

    const int bid = blockIdx.x;        // 128 blocks = (g,c,ai)
    const int ai = bid & 3;
    const int c  = (bid >> 2) & 7;
    const int g  = bid >> 5;
    const int tid = threadIdx.x;       // 512 = (j, l)
    const int j  = tid >> 6;           // 0..7
    const int l  = tid & 63;
    const int q  = l >> 4, m = l & 15;
    const int o  = g * 64 + ai * 16 + m;
    const int i  = c * 32 + q * 8 + j;

    float a[DKS];
#pragma unroll
    for (int d = 0; d < DKS; ++d) a[d] = 0.0f;

    const float4* Po = (const float4*)(P      + (size_t)(o * IN_CH + i) * KC);
    const float4* P0 = (const float4*)(P      + (size_t)i * KC);   // out-ch 0
    const float4* Wo = (const float4*)(weight + (size_t)(o * IN_CH + i) * KC);
#pragma unroll
    for (int kq = 0; kq < 4; ++kq) {
        float4 po = Po[kq], p0 = P0[kq], wo = Wo[kq];
        float pos[4]  = {po.x, po.y, po.z, po.w};
        float pos0[4] = {p0.x, p0.y, p0.z, p0.w};
        float ww[4]   = {wo.x, wo.y, wo.z, wo.w};
#pragma unroll
        for (int k = 0; k < 4; ++k) {
            float pp   = pos[k]  + (float)(DKS / 2);
            float p0v  = pos0[k] + (float)(DKS / 2);
            float frac = p0v - floorf(p0v);
            int   p1   = (int)floorf(pp);
            float w    = ww[k];
            a[p1] += w * (1.0f - frac);
            if (p1 + 1 < DKS) a[p1 + 1] += w * frac;
        }
    }
#pragma unroll
    for (int d = 0; d < DKS; ++d)
        Ls[d * 512 + l * 8 + j] = f2bf(a[d]);
    __syncthreads();

    // coalesced stores: per d, 256 uints (1 KB) at base + d*4 KB
    const size_t base = ((size_t)(g * 8 + c) * DKS) * 2048 + (size_t)ai * 512;
    for (int idx = tid; idx < DKS * 256; idx += 512) {
        int d = idx >> 8;
        int u = idx & 255;
        *(unsigned*)(kern_f + base + (size_t)d * 2048 + u * 2) =
            *(const unsigned*)(Ls + d * 512 + u * 2);
    }
}

// ---------------------------------------------------------------------------
// Kernel 2: implicit-GEMM conv, MFMA 16x16x32 bf16, K-split 2.
// 512 blocks = ks(2) x og(2) x tt(16) x batch(8), (ks,og) in LOW bits so
// each XCD sees one 1.08MB kern slice (L2-resident A).
// Block 256 thr = 4 waves (2 o-halves x 2 t-halves) -> tile 128o x 128t;
// wave tile 64o x 64t (acc 16 frags = 64 VGPR; ~150 total, no spill at
// the (256,2) 256-reg cap). 2 blocks/CU = 8 waves/CU = 2/SIMD.
// Each block accumulates 4 of the 8 i-chunks; epilogue atomicAdd into
// zeroed out (memset in kernel_launch); ks==0 adds bias.
// ---------------------------------------------------------------------------
__global__ __launch_bounds__(256, 2) void dcls_conv(
    const float* __restrict__ x,
    const unsigned short* __restrict__ kern_f,
    const float* __restrict__ bias,
    float* __restrict__ out)
{
    __shared__ unsigned short Xs[2][XS_ROWS * XS_STRIDE];   // 2 x 12.8 KB

    const int id    = blockIdx.x;            // 0..511
    const int ks    = id & 1;
    const int og    = (id >> 1) & 1;
    const int tt    = (id >> 2) & 15;
    const int batch = id >> 6;
    const int t0    = tt * TT;

    const int tid  = threadIdx.x;
    const int w    = tid >> 6;
    const int oh   = w & 1;        // o-half
    const int th   = w >> 1;       // t-half
    const int l    = tid & 63;
    const int quad = l >> 4;
    const int lm   = l & 15;
    const int wt   = th * 64;      // wave's local t base
    const int g    = og * 2 + oh;  // kern_f o-group (64 o's)

    f32x4 acc[4][4];
#pragma unroll
    for (int a = 0; a < 4; ++a)
#pragma unroll
        for (int b = 0; b < 4; ++b) acc[a][b] = (f32x4){0.f, 0.f, 0.f, 0.f};

    const unsigned short* kf0 = kern_f + ((size_t)g * 8 * DKS) * 2048 + (size_t)l * 8;

    // ---- stage chunk ks*4 into buf 0 ----
    {
        const int i0 = ks * 4 * 32;
#pragma unroll
        for (int it = 0; it < 10; ++it) {
            int idx = tid + it * 256;          // 0..2559
            int ip  = idx / XS_ROWS;           // i-pair 0..15
            int t   = idx - ip * XS_ROWS;      // 0..159
            int gg  = t0 - PAD + t;
            float v0 = 0.f, v1 = 0.f;
            if ((unsigned)gg < (unsigned)T_LEN) {
                const float* xb = x + ((size_t)(batch * IN_CH + i0 + ip * 2)) * T_LEN + gg;
                v0 = xb[0];
                v1 = xb[T_LEN];
            }
            *(unsigned*)(&Xs[0][t * XS_STRIDE + ip * 2]) =
                (unsigned)f2bf(v0) | ((unsigned)f2bf(v1) << 16);
        }
    }
    __syncthreads();

    for (int cc = 0; cc < 4; ++cc) {
        const int c = ks * 4 + cc;
        const unsigned short* kfc = kf0 + (size_t)c * DKS * 2048;
        const unsigned short* xsb = &Xs[cc & 1][quad * 8];

        // prefetch d=0 frags (A from global/L2, B from LDS)
        bf16x8 af_c[4], bf_c[4];
#pragma unroll
        for (int a = 0; a < 4; ++a)
            af_c[a] = *(const bf16x8*)(kfc + a * 512);
#pragma unroll
        for (int b = 0; b < 4; ++b)
            bf_c[b] = *(const bf16x8*)(xsb + (wt + b * 16 + lm) * XS_STRIDE);

        // ---- stage chunk cc+1 into the other buffer (hidden under MFMAs) ----
        if (cc < 3) {
            const int i0 = (c + 1) * 32;
#pragma unroll
            for (int it = 0; it < 10; ++it) {
                int idx = tid + it * 256;
                int ip  = idx / XS_ROWS;
                int t   = idx - ip * XS_ROWS;
                int gg  = t0 - PAD + t;
                float v0 = 0.f, v1 = 0.f;
                if ((unsigned)gg < (unsigned)T_LEN) {
                    const float* xb = x + ((size_t)(batch * IN_CH + i0 + ip * 2)) * T_LEN + gg;
                    v0 = xb[0];
                    v1 = xb[T_LEN];
                }
                *(unsigned*)(&Xs[(cc + 1) & 1][t * XS_STRIDE + ip * 2]) =
                    (unsigned)f2bf(v0) | ((unsigned)f2bf(v1) << 16);
            }
        }

        // ---- 33 d-steps, 1-deep pipelined A (L2) and B (LDS) ----
#pragma unroll
        for (int d = 0; d < DKS; ++d) {
            bf16x8 af_n[4], bf_n[4];
            if (d + 1 < DKS) {
#pragma unroll
                for (int a = 0; a < 4; ++a)
                    af_n[a] = *(const bf16x8*)(kfc + (size_t)(d + 1) * 2048 + a * 512);
#pragma unroll
                for (int b = 0; b < 4; ++b)
                    bf_n[b] = *(const bf16x8*)(xsb + (wt + b * 16 + lm + d + 1) * XS_STRIDE);
            }
#pragma unroll
            for (int a = 0; a < 4; ++a)
#pragma unroll
                for (int b = 0; b < 4; ++b)
                    acc[a][b] = __builtin_amdgcn_mfma_f32_16x16x32_bf16(
                        af_c[a], bf_c[b], acc[a][b], 0, 0, 0);
            if (d + 1 < DKS) {
#pragma unroll
                for (int a = 0; a < 4; ++a) af_c[a] = af_n[a];
#pragma unroll
                for (int b = 0; b < 4; ++b) bf_c[b] = bf_n[b];
            }
        }
        __syncthreads();
    }

    // ---- epilogue: atomic accumulate (K-split combine); ks==0 adds bias ----
#pragma unroll
    for (int a = 0; a < 4; ++a) {
#pragma unroll
        for (int r = 0; r < 4; ++r) {
            int o = og * 128 + oh * 64 + a * 16 + quad * 4 + r;
            float bv = (ks == 0) ? bias[o] : 0.0f;
            float* orow = out + ((size_t)(batch * OUT_CH + o)) * T_LEN + t0 + wt + lm;
#pragma unroll
            for (int b = 0; b < 4; ++b)
                atomicAdd(&orow[b * 16], acc[a][b][r] + bv);
        }
    }
}

extern "C" void kernel_launch(void* const* d_in, const int* in_sizes, int n_in,
                              void* d_out, int out_size, void* d_ws, size_t ws_size,
                              hipStream_t stream) {
    const float* x      = (const float*)d_in[0];
    const float* weight = (const float*)d_in[1];
    const float* P      = (const float*)d_in[2];
    const float* bias   = (const float*)d_in[3];
    float*       out    = (float*)d_out;
    unsigned short* kern_f = (unsigned short*)d_ws;   // 4.33 MB

    // out is re-poisoned before every launch; K-split atomics need zeros.
    hipMemsetAsync(out, 0, (size_t)out_size * sizeof(float), stream);

    hipLaunchKernelGGL(build_kern, dim3(128), dim3(512), 0, stream,
                       weight, P, kern_f);

    hipLaunchKernelGGL(dcls_conv, dim3(512), dim3(256), 0, stream,
                       x, kern_f, bias, out);
}

// Round 7
// 255.170 us; speedup vs baseline: 1.2589x; 1.0204x over previous
//
#include <hip/hip_runtime.h>
#include <math.h>

#define N_BATCH 8
#define IN_CH   256
#define OUT_C   256
#define T_LEN   2048
#define DKS     33
#define PAD     16
#define KC      16

#define TT 128        // t per block
#define XS_ROWS 160   // TT + 2*PAD
#define XS_STRIDE 40  // ushort elems per row (80 B, 16B-aligned)

typedef __attribute__((ext_vector_type(8))) short bf16x8;
typedef __attribute__((ext_vector_type(4))) float f32x4;

__device__ __forceinline__ unsigned short f2bf(float f) {
    unsigned u = __builtin_bit_cast(unsigned, f);
    unsigned r = (u + 0x7FFFu + ((u >> 16) & 1u)) >> 16;   // RNE
    return (unsigned short)r;
}

// ---------------------------------------------------------------------------
// Kernel 1: dense conv kernel in bf16, fragment-ready global layout
//   elem(o,i,d) at ((g*8+c)*33+d)*2048 + ai*512 + (q*16+m)*8 + j
//   g=o>>6, ai=(o>>4)&3, m=o&15, c=i>>5, q=(i&31)>>3, j=i&7.
// 128 blocks x 512 thr, tid=(m,il): consecutive lanes read consecutive i
// -> 2KB-contiguous global loads; LDS bounce -> 1KB-run coalesced stores.
// Reference semantics: frac from out-channel 0; second tap dropped when
// p1+1 == 33.
// ---------------------------------------------------------------------------
__global__ __launch_bounds__(512) void build_kern(
    const float* __restrict__ weight,
    const float* __restrict__ P,
    unsigned short* __restrict__ kern_f)
{
    __shared__ unsigned short Ls[DKS * 512];   // 33.8 KB

    const int bid = blockIdx.x;        // 128 = (g,c,ai)
    const int ai = bid & 3;
    const int c  = (bid >> 2) & 7;
    const int g  = bid >> 5;
    const int tid = threadIdx.x;       // 512 = (m, il)
    const int m  = tid >> 5;           // 0..15
    const int il = tid & 31;           // 0..31
    const int q  = il >> 3, j = il & 7;
    const int o  = g * 64 + ai * 16 + m;
    const int i  = c * 32 + il;

    float a[DKS];
#pragma unroll
    for (int d = 0; d < DKS; ++d) a[d] = 0.0f;

    const float4* Po = (const float4*)(P      + (size_t)(o * IN_CH + i) * KC);
    const float4* P0 = (const float4*)(P      + (size_t)i * KC);   // out-ch 0
    const float4* Wo = (const float4*)(weight + (size_t)(o * IN_CH + i) * KC);
#pragma unroll
    for (int kq = 0; kq < 4; ++kq) {
        float4 po = Po[kq], p0 = P0[kq], wo = Wo[kq];
        float pos[4]  = {po.x, po.y, po.z, po.w};
        float pos0[4] = {p0.x, p0.y, p0.z, p0.w};
        float ww[4]   = {wo.x, wo.y, wo.z, wo.w};
#pragma unroll
        for (int k = 0; k < 4; ++k) {
            float pp   = pos[k]  + (float)(DKS / 2);
            float p0v  = pos0[k] + (float)(DKS / 2);
            float frac = p0v - floorf(p0v);
            int   p1   = (int)floorf(pp);
            float w    = ww[k];
            a[p1] += w * (1.0f - frac);
            if (p1 + 1 < DKS) a[p1 + 1] += w * frac;
        }
    }
#pragma unroll
    for (int d = 0; d < DKS; ++d)
        Ls[d * 512 + (q * 16 + m) * 8 + j] = f2bf(a[d]);
    __syncthreads();

    // coalesced stores: per d, 256 uints (1 KB) at base + d*4KB
    const size_t base = ((size_t)(g * 8 + c) * DKS) * 2048 + (size_t)ai * 512;
    for (int idx = tid; idx < DKS * 256; idx += 512) {
        int d = idx >> 8;
        int u = idx & 255;
        *(unsigned*)(kern_f + base + (size_t)d * 2048 + u * 2) =
            *(const unsigned*)(Ls + d * 512 + u * 2);
    }
}

// ---------------------------------------------------------------------------
// Kernel 2: implicit-GEMM conv, MFMA 16x16x32 bf16, K-split 2.
// Grid 1024 = og(4) x ks(2) x tt(16) x batch(8); (og,ks) in id&7 so each
// XCD reads one 0.54MB kern slice (L2-resident).
// Block 256 thr = 4 waves, all on the same 64 o's (A-frags identical across
// waves -> L1 broadcast); wave tile 64o x 32t (acc 8 frags = 32 regs,
// ~116 VGPR total, no spill at the (256,4) 128-reg cap).
// 4 blocks/CU = 16 waves/CU = 4/SIMD (2x round 2's occupancy; MfmaUtil has
// tracked waves/CU linearly in every round -> predict ~2x).
// Each block accumulates 4 of 8 i-chunks; atomicAdd combine into zeroed out;
// ks==0 adds bias.
// ---------------------------------------------------------------------------
__global__ __launch_bounds__(256, 4) void dcls_conv(
    const float* __restrict__ x,
    const unsigned short* __restrict__ kern_f,
    const float* __restrict__ bias,
    float* __restrict__ out)
{
    __shared__ unsigned short Xs[XS_ROWS * XS_STRIDE];   // 12.8 KB

    const int id    = blockIdx.x;            // 0..1023
    const int og    = id & 3;
    const int ks    = (id >> 2) & 1;
    const int tt    = (id >> 3) & 15;
    const int batch = id >> 7;
    const int t0    = tt * TT;
    const int o0    = og * 64;

    const int tid  = threadIdx.x;
    const int w    = tid >> 6;
    const int l    = tid & 63;
    const int quad = l >> 4;
    const int lm   = l & 15;
    const int wt   = w * 32;          // wave's local t base

    f32x4 acc[4][2];
#pragma unroll
    for (int a = 0; a < 4; ++a)
#pragma unroll
        for (int b = 0; b < 2; ++b) acc[a][b] = (f32x4){0.f, 0.f, 0.f, 0.f};

    const unsigned short* kf0 = kern_f + ((size_t)og * 8 * DKS) * 2048 + (size_t)l * 8;

    for (int cc = 0; cc < 4; ++cc) {
        const int c = ks * 4 + cc;
        __syncthreads();   // previous chunk's reads done before overwrite

        // ---- stage Xs: 32 i x 160 t, transposed, fp32 -> bf16 ----
        const int i0 = c * 32;
#pragma unroll
        for (int it = 0; it < 10; ++it) {
            int idx = tid + it * 256;          // 0..2559
            int ip  = idx / XS_ROWS;           // i-pair 0..15
            int t   = idx - ip * XS_ROWS;      // 0..159
            int gg  = t0 - PAD + t;
            float v0 = 0.f, v1 = 0.f;
            if ((unsigned)gg < (unsigned)T_LEN) {
                const float* xb = x + ((size_t)(batch * IN_CH + i0 + ip * 2)) * T_LEN + gg;
                v0 = xb[0];
                v1 = xb[T_LEN];
            }
            *(unsigned*)(&Xs[t * XS_STRIDE + ip * 2]) =
                (unsigned)f2bf(v0) | ((unsigned)f2bf(v1) << 16);
        }
        __syncthreads();

        // ---- 33 barrier-free d-steps: 4 A (global/L1, shared by all waves),
        //      2 B (ds_read_b128), 8 MFMA ----
        const unsigned short* kfc = kf0 + (size_t)c * DKS * 2048;
        for (int d = 0; d < DKS; ++d) {
            bf16x8 af[4];
#pragma unroll
            for (int a = 0; a < 4; ++a)
                af[a] = *(const bf16x8*)(kfc + (size_t)d * 2048 + a * 512);
            bf16x8 bf[2];
#pragma unroll
            for (int b = 0; b < 2; ++b)
                bf[b] = *(const bf16x8*)(&Xs[(wt + b * 16 + lm + d) * XS_STRIDE + quad * 8]);
#pragma unroll
            for (int a = 0; a < 4; ++a)
#pragma unroll
                for (int b = 0; b < 2; ++b)
                    acc[a][b] = __builtin_amdgcn_mfma_f32_16x16x32_bf16(
                        af[a], bf[b], acc[a][b], 0, 0, 0);
        }
    }

    // ---- epilogue: atomic K-split combine; ks==0 adds bias ----
#pragma unroll
    for (int a = 0; a < 4; ++a) {
#pragma unroll
        for (int r = 0; r < 4; ++r) {
            int o = o0 + a * 16 + quad * 4 + r;
            float bv = (ks == 0) ? bias[o] : 0.0f;
            float* orow = out + ((size_t)(batch * OUT_C + o)) * T_LEN + t0 + wt + lm;
#pragma unroll
            for (int b = 0; b < 2; ++b)
                atomicAdd(&orow[b * 16], acc[a][b][r] + bv);
        }
    }
}

extern "C" void kernel_launch(void* const* d_in, const int* in_sizes, int n_in,
                              void* d_out, int out_size, void* d_ws, size_t ws_size,
                              hipStream_t stream) {
    const float* x      = (const float*)d_in[0];
    const float* weight = (const float*)d_in[1];
    const float* P      = (const float*)d_in[2];
    const float* bias   = (const float*)d_in[3];
    float*       out    = (float*)d_out;
    unsigned short* kern_f = (unsigned short*)d_ws;   // 4.33 MB

    // K-split atomics need zeroed output (harness re-poisons to 0xAA).
    hipMemsetAsync(out, 0, (size_t)out_size * sizeof(float), stream);

    hipLaunchKernelGGL(build_kern, dim3(128), dim3(512), 0, stream,
                       weight, P, kern_f);

    hipLaunchKernelGGL(dcls_conv, dim3(1024), dim3(256), 0, stream,
                       x, kern_f, bias, out);
}

// Round 8
// 252.510 us; speedup vs baseline: 1.2721x; 1.0105x over previous
//
#include <hip/hip_runtime.h>
#include <math.h>

#define N_BATCH 8
#define IN_CH   256
#define OUT_C   256
#define T_LEN   2048
#define DKS     33
#define PAD     16
#define KC      16

#define TT 256        // t per block (2 waves x 128)
#define XR 288        // TT + 2*PAD rows in LDS
#define XS_STRIDE 40  // ushort elems per row (80 B, 16B-aligned)

typedef __attribute__((ext_vector_type(8))) short bf16x8;
typedef __attribute__((ext_vector_type(4))) float f32x4;

__device__ __forceinline__ unsigned short f2bf(float f) {
    unsigned u = __builtin_bit_cast(unsigned, f);
    unsigned r = (u + 0x7FFFu + ((u >> 16) & 1u)) >> 16;   // RNE
    return (unsigned short)r;
}

// ---------------------------------------------------------------------------
// Kernel 1 (v6): dense conv kernel in bf16, fragment-ready global layout
//   elem(o,i,d) at ((g*8+c)*33+d)*2048 + ai*512 + (q*16+m)*8 + j
// BRANCHLESS rewrite: previous versions did a[p1] += ... with runtime p1 —
// dynamic indexing into a register array, which the compiler can lower to
// SCRATCH (global memory) -> suspected hidden ~80us cost. Now each tap d is
// computed directly as sum_k w_k * (sel(p1==d)*(1-frac) + sel(p1==d-1)*frac)
// -> pure v_cmp/v_cndmask/v_fma, no private arrays with dynamic subscripts.
// Reference semantics preserved: frac from out-channel 0; second tap dropped
// when p1+1 == 33 (p1==32, d never reaches 33).
// ---------------------------------------------------------------------------
__global__ __launch_bounds__(512) void build_kern(
    const float* __restrict__ weight,
    const float* __restrict__ P,
    unsigned short* __restrict__ kern_f)
{
    __shared__ unsigned short Ls[DKS * 512];   // 33.8 KB

    const int bid = blockIdx.x;        // 128 = (g,c,ai)
    const int ai = bid & 3;
    const int c  = (bid >> 2) & 7;
    const int g  = bid >> 5;
    const int tid = threadIdx.x;       // 512 = (m, il)
    const int m  = tid >> 5;           // 0..15
    const int il = tid & 31;           // 0..31
    const int q  = il >> 3, j = il & 7;
    const int o  = g * 64 + ai * 16 + m;
    const int i  = c * 32 + il;

    // load the 16 taps' (p1, frac, w) into static registers
    float w_[KC], fr_[KC];
    int   p1_[KC];
    const float* Po = P      + (size_t)(o * IN_CH + i) * KC;
    const float* P0 = P      + (size_t)i * KC;           // out-channel 0
    const float* Wo = weight + (size_t)(o * IN_CH + i) * KC;
#pragma unroll
    for (int k = 0; k < KC; ++k) {
        float pp  = Po[k] + (float)(DKS / 2);
        float p0v = P0[k] + (float)(DKS / 2);
        fr_[k] = p0v - floorf(p0v);
        p1_[k] = (int)floorf(pp);
        w_[k]  = Wo[k];
    }

#pragma unroll
    for (int d = 0; d < DKS; ++d) {
        float s = 0.0f;
#pragma unroll
        for (int k = 0; k < KC; ++k) {
            float sel = (p1_[k] == d)     ? (1.0f - fr_[k])
                      : (p1_[k] == d - 1) ? fr_[k] : 0.0f;
            s += w_[k] * sel;
        }
        Ls[d * 512 + (q * 16 + m) * 8 + j] = f2bf(s);
    }
    __syncthreads();

    // coalesced stores: per d, 256 uints (1 KB runs)
    const size_t base = ((size_t)(g * 8 + c) * DKS) * 2048 + (size_t)ai * 512;
    for (int idx = tid; idx < DKS * 256; idx += 512) {
        int d = idx >> 8;
        int u = idx & 255;
        *(unsigned*)(kern_f + base + (size_t)d * 2048 + u * 2) =
            *(const unsigned*)(Ls + d * 512 + u * 2);
    }
}

// ---------------------------------------------------------------------------
// Kernel 2: implicit-GEMM conv, MFMA 16x16x32 bf16, K-split 2.
// THE round-8 change: wave tile 64o x 128t (was 64o x 32t) -> A-bytes per
// MFMA drop 512B -> 128B, under the measured ~64 B/cyc/CU L1 delivery limit
// (r7: L1-saturated at MfmaUtil 16%). B stays in LDS (256 B/MFMA, separate
// pipe). Block = 128 thr = 2 waves (t-split, same o -> one shared A stream).
// acc = 4x8 frags = 128 VGPRs; B-loads ordered b-outer with ONE live B-frag
// -> ~185 live regs < 256 cap of __launch_bounds__(128,2). No B prefetch.
// Grid 512 = og(4) x ks(2) x tt(8) x batch(8), (og,ks) in id&7 -> per-XCD
// kern slice 1.08MB, L2-resident. 4 blocks/CU = 8 waves/CU = 2/SIMD.
// K-split combine: atomicAdd into zeroed out; ks==0 adds bias.
// ---------------------------------------------------------------------------
__global__ __launch_bounds__(128, 2) void dcls_conv(
    const float* __restrict__ x,
    const unsigned short* __restrict__ kern_f,
    const float* __restrict__ bias,
    float* __restrict__ out)
{
    __shared__ unsigned short Xs[XR * XS_STRIDE];   // 23.0 KB

    const int id    = blockIdx.x;            // 0..511
    const int og    = id & 3;
    const int ks    = (id >> 2) & 1;
    const int tt    = (id >> 3) & 7;
    const int batch = id >> 6;
    const int t0    = tt * TT;
    const int o0    = og * 64;

    const int tid  = threadIdx.x;
    const int w    = tid >> 6;        // wave 0/1
    const int l    = tid & 63;
    const int quad = l >> 4;
    const int lm   = l & 15;
    const int wt   = w * 128;         // wave's local t base

    f32x4 acc[4][8];
#pragma unroll
    for (int a = 0; a < 4; ++a)
#pragma unroll
        for (int b = 0; b < 8; ++b) acc[a][b] = (f32x4){0.f, 0.f, 0.f, 0.f};

    const unsigned short* kf0 = kern_f + ((size_t)og * 8 * DKS) * 2048 + (size_t)l * 8;

    for (int cc = 0; cc < 4; ++cc) {
        const int c = ks * 4 + cc;
        __syncthreads();   // previous chunk's reads done before overwrite

        // ---- stage Xs: 32 i x 288 t, transposed, fp32 -> bf16 ----
        const int i0 = c * 32;
#pragma unroll
        for (int it = 0; it < 36; ++it) {
            int idx = tid + it * 128;          // 0..4607
            int ip  = idx / XR;                // i-pair 0..15
            int t   = idx - ip * XR;           // 0..287
            int gg  = t0 - PAD + t;
            float v0 = 0.f, v1 = 0.f;
            if ((unsigned)gg < (unsigned)T_LEN) {
                const float* xb = x + ((size_t)(batch * IN_CH + i0 + ip * 2)) * T_LEN + gg;
                v0 = xb[0];
                v1 = xb[T_LEN];
            }
            *(unsigned*)(&Xs[t * XS_STRIDE + ip * 2]) =
                (unsigned)f2bf(v0) | ((unsigned)f2bf(v1) << 16);
        }
        __syncthreads();

        // ---- 33 d-steps: 4 A (global/L1, 1-deep prefetch), 8x(1 B + 4 MFMA) ----
        const unsigned short* kfc = kf0 + (size_t)c * DKS * 2048;
        bf16x8 af_c[4], af_n[4];
#pragma unroll
        for (int a = 0; a < 4; ++a)
            af_c[a] = *(const bf16x8*)(kfc + a * 512);

        for (int d = 0; d < DKS; ++d) {
            if (d + 1 < DKS) {
#pragma unroll
                for (int a = 0; a < 4; ++a)
                    af_n[a] = *(const bf16x8*)(kfc + (size_t)(d + 1) * 2048 + a * 512);
            }
#pragma unroll
            for (int b = 0; b < 8; ++b) {
                bf16x8 bf = *(const bf16x8*)(
                    &Xs[(wt + b * 16 + lm + d) * XS_STRIDE + quad * 8]);
#pragma unroll
                for (int a = 0; a < 4; ++a)
                    acc[a][b] = __builtin_amdgcn_mfma_f32_16x16x32_bf16(
                        af_c[a], bf, acc[a][b], 0, 0, 0);
            }
#pragma unroll
            for (int a = 0; a < 4; ++a) af_c[a] = af_n[a];
        }
    }

    // ---- epilogue: atomic K-split combine; ks==0 adds bias ----
#pragma unroll
    for (int a = 0; a < 4; ++a) {
#pragma unroll
        for (int r = 0; r < 4; ++r) {
            int o = o0 + a * 16 + quad * 4 + r;
            float bv = (ks == 0) ? bias[o] : 0.0f;
            float* orow = out + ((size_t)(batch * OUT_C + o)) * T_LEN + t0 + wt + lm;
#pragma unroll
            for (int b = 0; b < 8; ++b)
                atomicAdd(&orow[b * 16], acc[a][b][r] + bv);
        }
    }
}

extern "C" void kernel_launch(void* const* d_in, const int* in_sizes, int n_in,
                              void* d_out, int out_size, void* d_ws, size_t ws_size,
                              hipStream_t stream) {
    const float* x      = (const float*)d_in[0];
    const float* weight = (const float*)d_in[1];
    const float* P      = (const float*)d_in[2];
    const float* bias   = (const float*)d_in[3];
    float*       out    = (float*)d_out;
    unsigned short* kern_f = (unsigned short*)d_ws;   // 4.33 MB

    // K-split atomics need zeroed output (harness re-poisons to 0xAA).
    hipMemsetAsync(out, 0, (size_t)out_size * sizeof(float), stream);

    hipLaunchKernelGGL(build_kern, dim3(128), dim3(512), 0, stream,
                       weight, P, kern_f);

    hipLaunchKernelGGL(dcls_conv, dim3(512), dim3(128), 0, stream,
                       x, kern_f, bias, out);
}